// Round 10
// baseline (226.226 us; speedup 1.0000x reference)
//
#include <hip/hip_runtime.h>

#define PI_F 3.14159265358979323846f

typedef short bf16x8 __attribute__((ext_vector_type(8)));
typedef float f32x4 __attribute__((ext_vector_type(4)));

#define MFMA16(acc, a, b) \
  acc = __builtin_amdgcn_mfma_f32_16x16x32_bf16(a, b, acc, 0, 0, 0)

// ---------------- workspace layout (float offsets) ----------------
#define WS_SPEC   0u          // 32*128*1024  [b][t][k]; dead after k_proj_in ->
                              // reused for the Aext bf16 packs (k_apack/k_conv)
#define WS_H0     4194304u    // 32*32*128    [b][o][t]
#define WS_ACC    4325376u    // 32*128*32    [b][t][o]
#define WS_V      4456448u    // 32*32*128    [b][c][t]; ALSO: k_prep stashes the
                              // chain-weight bf16 packs in the first 16384 floats
#define WS_WTIN   4587520u    // 1024*32      [k][o]
#define WS_WST    4620288u    // 32*256       [m][o2]
#define WS_WDT    4628480u    // 256*32       [o2][c]
#define WS_FRAMES 4636672u    // 32*32*2048   [c][f][j]; after k_res_assemble this
                              // region is DEAD -> reused for Bh/Bl bf16 packs
#define WS_RES    6733824u    // 32*32768     [c][s]
// total 7782400 floats = ~29.7 MB

// ---- 2048-pt complex DIT FFT, input already in bit-reversed order, 256 thr ----
__device__ __forceinline__ void fft2048_stages(float2* buf, int tid) {
  for (int stage = 0; stage < 11; ++stage) {
    int half = 1 << stage;
    float base = -PI_F / (float)half;   // -2*pi/len
    for (int t = tid; t < 1024; t += 256) {
      int j  = t & (half - 1);
      int i0 = ((t >> stage) << (stage + 1)) + j;
      int i1 = i0 + half;
      float s, c;
      __sincosf(base * (float)j, &s, &c);   // e^{-i*2pi/len*j} = c + i*s
      float2 u = buf[i0];
      float2 w = buf[i1];
      float tr = c * w.x - s * w.y;
      float ti = c * w.y + s * w.x;
      buf[i0] = make_float2(u.x + tr, u.y + ti);
      buf[i1] = make_float2(u.x - tr, u.y - ti);
    }
    __syncthreads();
  }
}

// ---------------- fused FFT kernel: STFT pairs + resonance-frame pairs ----------------
__global__ __launch_bounds__(256) void k_fft(const float* __restrict__ audio,
                                             const float* __restrict__ resin,
                                             float* __restrict__ spec,
                                             float* __restrict__ frames) {
  __shared__ float2 buf[2048];
  int blk = blockIdx.x;
  if (blk < 2048) {
    int b  = blk >> 6;
    int f0 = (blk & 63) * 2;      // frames f0, f0+1
    for (int j = threadIdx.x; j < 2048; j += 256) {
      float h = 0.5f - 0.5f * __cosf(0.0030679615757712823f * (float)j); // 2pi/2048
      int i1 = f0 * 256 + j;
      int i2 = i1 + 256;
      float a1 = (i1 < 32768) ? audio[b * 32768 + i1] : 0.f;
      float a2 = (i2 < 32768) ? audio[b * 32768 + i2] : 0.f;
      buf[__brev((unsigned)j) >> 21] = make_float2(a1 * h, a2 * h);
    }
    __syncthreads();
    fft2048_stages(buf, threadIdx.x);
    const float scale = 0.5f * 0.022097086912079608f;  // 0.5 / sqrt(2048)
    for (int k = threadIdx.x; k < 1024; k += 256) {
      float2 zk = buf[k];
      float2 zn = buf[(2048 - k) & 2047];
      float f1r = zk.x + zn.x, f1i = zk.y - zn.y;
      float f2r = zk.y + zn.y, f2i = zk.x - zn.x;
      spec[(b * 128 + f0) * 1024 + k]     = sqrtf(f1r * f1r + f1i * f1i) * scale;
      spec[(b * 128 + f0 + 1) * 1024 + k] = sqrtf(f2r * f2r + f2i * f2i) * scale;
    }
  } else {
    int r = blk - 2048;           // 0..511
    int c = r >> 4;
    int g = r & 15;               // frames 2g (exp 2g+1), 2g+1 (exp 2g+2)
    float e1 = (float)(2 * g + 1);
    for (int k = threadIdx.x; k < 2048; k += 256) {
      int kk = (k <= 1024) ? k : 2048 - k;   // Hermitian (real) extension
      float cv = resin[c * 1025 + kk];
      cv = fminf(fmaxf(cv, 0.f), 0.9999f);
      float m1 = __powf(cv, e1);
      float m2 = m1 * cv;
      buf[__brev((unsigned)k) >> 21] = make_float2(m1, m2);
    }
    __syncthreads();
    fft2048_stages(buf, threadIdx.x);
    for (int j = threadIdx.x; j < 2048; j += 256) {
      float h  = 0.5f - 0.5f * __cosf(0.0030679615757712823f * (float)j);
      float sc = h * (1.f / 2048.f);
      float2 z = buf[j];
      frames[(c * 32 + 2 * g) * 2048 + j]     = z.x * sc;
      frames[(c * 32 + 2 * g + 1) * 2048 + j] = z.y * sc;
    }
  }
}

// ---------------- weight transposes + chain-weight bf16 hi/lo packs ----------------
__global__ __launch_bounds__(256) void k_prep(const float* __restrict__ Win,
                                              const float* __restrict__ Ws,
                                              const float* __restrict__ Wd,
                                              const float* __restrict__ bwIn,
                                              float* __restrict__ WT,
                                              float* __restrict__ WsT,
                                              float* __restrict__ WdT,
                                              short* __restrict__ Whg,
                                              short* __restrict__ Wlg) {
  int i = blockIdx.x * 256 + threadIdx.x;
  if (i < 32768) { int o = i >> 10, k = i & 1023; WT[k * 32 + o] = Win[i]; }
  if (i < 8192)  { int o2 = i >> 5, m = i & 31;   WsT[m * 256 + o2] = Ws[i]; }
  if (i < 8192)  { int c = i >> 8, o2 = i & 255;  WdT[o2 * 32 + c] = Wd[i]; }
  if (i < 16384) {
    // i = ((s*32+o)*32+m)*2 + w
    int w = i & 1, m = (i >> 1) & 31, o = (i >> 6) & 31, s = i >> 11;
    float val = bwIn[i];
    unsigned bits = __float_as_uint(val);
    float rem = val - __uint_as_float(bits & 0xffff0000u);
    int row = (s * 2 + w) * 32 + o;
    Whg[row * 32 + m] = (short)(bits >> 16);
    Wlg[row * 32 + m] = (short)(__float_as_uint(rem) >> 16);
  }
}

// ---------------- proj_in: h0[b,o,t] = sum_k WT[k][o]*spec[b,t,k] + bias ----------------
__global__ __launch_bounds__(256) void k_proj_in(const float* __restrict__ spec,
                                                 const float* __restrict__ WT,
                                                 const float* __restrict__ bias,
                                                 float* __restrict__ h0) {
  __shared__ float specL[8][1024];
  __shared__ float red[32][8][8];   // [o][tt][p]
  int b  = blockIdx.x >> 4;
  int t0 = (blockIdx.x & 15) * 8;
  for (int i = threadIdx.x; i < 8192; i += 256) {
    int tt = i >> 10, k = i & 1023;
    specL[tt][k] = spec[(b * 128 + t0 + tt) * 1024 + k];
  }
  __syncthreads();
  int o = threadIdx.x & 31, p = threadIdx.x >> 5;
  float part[8] = {0.f,0.f,0.f,0.f,0.f,0.f,0.f,0.f};
  for (int i = 0; i < 128; ++i) {
    int k = p * 128 + ((i + p * 4) & 127);   // stagger: conflict-free banks across p
    float w = WT[k * 32 + o];
#pragma unroll
    for (int tt = 0; tt < 8; ++tt) part[tt] += w * specL[tt][k];
  }
#pragma unroll
  for (int tt = 0; tt < 8; ++tt) red[o][tt][p] = part[tt];
  __syncthreads();
  int oo = threadIdx.x >> 3, tt2 = threadIdx.x & 7;
  float s = bias[oo];
#pragma unroll
  for (int p2 = 0; p2 < 8; ++p2) s += red[oo][tt2][p2];
  h0[b * 4096 + oo * 128 + t0 + tt2] = s;
}

// ---------------- 8-block anticausal chain as per-step MFMA GEMM pairs ----------------
__global__ __launch_bounds__(1024) void k_chain(const float* __restrict__ h0,
                                                const short* __restrict__ Whg,
                                                const short* __restrict__ Wlg,
                                                const float* __restrict__ bb,
                                                float* __restrict__ accout) {
  __shared__ __align__(16) short Hh[192 * 40];   // rows stride 40 bf16 (80 B)
  __shared__ __align__(16) short Hl[192 * 40];
  __shared__ float Hf[128 * 33];                 // fp32 H for exact residual
  __shared__ float bL[256];
  __shared__ float red[16];
  int b = blockIdx.x, tid = threadIdx.x;

  for (int i = tid; i < 4096; i += 1024) {
    int t = i & 127;                 // h0 layout [o][t]
    int o = i >> 7;
    float val = h0[b * 4096 + i];
    Hf[t * 33 + o] = val;
    unsigned bits = __float_as_uint(val);
    float rem = val - __uint_as_float(bits & 0xffff0000u);
    Hh[t * 40 + o] = (short)(bits >> 16);
    Hl[t * 40 + o] = (short)(__float_as_uint(rem) >> 16);
  }
  for (int i = tid; i < 64 * 40; i += 1024) {    // zero pad rows 128..191
    Hh[128 * 40 + i] = 0;
    Hl[128 * 40 + i] = 0;
  }
  if (tid < 256) bL[tid] = bb[tid];
  __syncthreads();

  int wave = tid >> 6, lane = tid & 63;
  int quad = lane >> 4, l15 = lane & 15;
  int t0 = (wave & 7) * 16, o0 = (wave >> 3) * 16;
  int tD = t0 + quad * 4;          // D rows tD..tD+3
  int oD = o0 + l15;               // D col

  const bf16x8* Hh8 = (const bf16x8*)Hh;   // unit = row*5 + quad (40 bf16 = 5 units)
  const bf16x8* Hl8 = (const bf16x8*)Hl;
  const bf16x8* Wh8 = (const bf16x8*)Whg;  // unit = row*4 + quad (32 bf16 = 4 units)
  const bf16x8* Wl8 = (const bf16x8*)Wlg;

  float accsum[4] = {0.f, 0.f, 0.f, 0.f};
  const int DIL[8] = {1, 2, 4, 8, 16, 32, 64, 1};

#pragma unroll
  for (int s = 0; s < 8; ++s) {
    int arow = t0 + l15;
    int frow = arow + DIL[s];        // <= 191, pad rows give zeros
    bf16x8 Ah = Hh8[arow * 5 + quad];
    bf16x8 Al = Hl8[arow * 5 + quad];
    bf16x8 Fh = Hh8[frow * 5 + quad];
    bf16x8 Fl = Hl8[frow * 5 + quad];
    int w0row = ((s * 2 + 0) * 32 + oD) * 4 + quad;
    int w1row = ((s * 2 + 1) * 32 + oD) * 4 + quad;
    bf16x8 B0h = Wh8[w0row], B0l = Wl8[w0row];
    bf16x8 B1h = Wh8[w1row], B1l = Wl8[w1row];
    float bias = bL[s * 32 + oD];
    f32x4 acc = {bias, bias, bias, bias};
    MFMA16(acc, Ah, B0h); MFMA16(acc, Ah, B0l); MFMA16(acc, Al, B0h);
    MFMA16(acc, Fh, B1h); MFMA16(acc, Fh, B1l); MFMA16(acc, Fl, B1h);
    float hnew[4], lmax = 0.f;
#pragma unroll
    for (int r = 0; r < 4; ++r) {
      float sv = acc[r];
      sv = (sv > 0.f) ? sv : 0.2f * sv;       // leaky_relu 0.2
      sv += Hf[(tD + r) * 33 + oD];           // residual (exact fp32)
      hnew[r] = sv;
      lmax = fmaxf(lmax, fabsf(sv));
    }
#pragma unroll
    for (int off = 32; off > 0; off >>= 1)
      lmax = fmaxf(lmax, __shfl_down(lmax, off, 64));
    if (lane == 0) red[wave] = lmax;
    __syncthreads();                 // red visible; all H reads of this step done
    float mx = red[0];
#pragma unroll
    for (int i = 1; i < 16; ++i) mx = fmaxf(mx, red[i]);
    float nm = 1.f / (mx + 1e-8f);
#pragma unroll
    for (int r = 0; r < 4; ++r) {
      float hv = hnew[r] * nm;
      accsum[r] += hv;
      int t = tD + r;
      Hf[t * 33 + oD] = hv;
      unsigned bits = __float_as_uint(hv);
      float rem = hv - __uint_as_float(bits & 0xffff0000u);
      Hh[t * 40 + oD] = (short)(bits >> 16);
      Hl[t * 40 + oD] = (short)(__float_as_uint(rem) >> 16);
    }
    __syncthreads();                 // new H visible for next step
  }
#pragma unroll
  for (int r = 0; r < 4; ++r)
    accout[b * 4096 + (tD + r) * 32 + oD] = accsum[r];
}

// ---------------- sparse (relu proj 32->256, to d_out) + dense (256->32, to ws) ----------------
__global__ __launch_bounds__(256) void k_sparse_dense(const float* __restrict__ acc,
                                                      const float* __restrict__ WsT,
                                                      const float* __restrict__ bs,
                                                      const float* __restrict__ WdT,
                                                      const float* __restrict__ bd,
                                                      float* __restrict__ out_sparse,
                                                      float* __restrict__ v) {
  __shared__ float accL[32];
  __shared__ float sL[256];
  __shared__ float red[8][32];
  int b = blockIdx.x >> 7, t = blockIdx.x & 127;
  int tid = threadIdx.x;
  if (tid < 32) accL[tid] = acc[b * 4096 + t * 32 + tid];
  __syncthreads();
  float s = bs[tid];
  for (int m = 0; m < 32; ++m) s += WsT[m * 256 + tid] * accL[m];
  s = fmaxf(s, 0.f);
  out_sparse[b * 32768 + tid * 128 + t] = s;
  sL[tid] = s;
  __syncthreads();
  int c = tid & 31, p = tid >> 5;
  float part = 0.f;
  for (int j = 0; j < 32; ++j) {
    int o2 = p * 32 + j;
    part += WdT[o2 * 32 + c] * sL[o2];
  }
  red[p][c] = part;
  __syncthreads();
  if (tid < 32) {
    float vv = bd[tid];
    for (int p2 = 0; p2 < 8; ++p2) vv += red[p2][tid];
    v[b * 4096 + tid * 128 + t] = vv;
  }
}

// ---------------- overlap-add (hop 1024): at most 2 frames per sample ----------------
__global__ __launch_bounds__(256) void k_res_assemble(const float* __restrict__ frames,
                                                      float* __restrict__ res) {
  int i = blockIdx.x * 256 + threadIdx.x;   // 0 .. 32*32768
  int c = i >> 15, s = i & 32767;
  int g = s >> 10, j0 = s & 1023;
  float v = frames[(c * 32 + g) * 2048 + j0];
  if (g > 0) v += frames[(c * 32 + g - 1) * 2048 + j0 + 1024];
  res[i] = v;
}

// ---------------- B-pack: res -> bf16 hi/lo in MFMA b-fragment layout ----------------
__global__ __launch_bounds__(256) void k_bpack(const float* __restrict__ res,
                                               short* __restrict__ Bh,
                                               short* __restrict__ Bl) {
  int c = blockIdx.x >> 4, o = blockIdx.x & 15;
  int r = threadIdx.x;
  bf16x8 hv, lv;
#pragma unroll
  for (int j = 0; j < 8; ++j) {
    float val = res[c * 32768 + (8 * o + j) * 256 + r];
    unsigned bits = __float_as_uint(val);
    float rem = val - __uint_as_float(bits & 0xffff0000u);
    hv[j] = (short)(bits >> 16);
    lv[j] = (short)(__float_as_uint(rem) >> 16);
  }
  int unit = (blockIdx.x * 16 + (r >> 4)) * 16 + (r & 15);
  ((bf16x8*)Bh)[unit] = hv;
  ((bf16x8*)Bl)[unit] = lv;
}

// ---------------- A-pack: extended Toeplitz Aext[b][m'][kk], bf16 hi/lo ----------------
__global__ __launch_bounds__(256) void k_apack(const float* __restrict__ v,
                                               short* __restrict__ Ahx,
                                               short* __restrict__ Alx) {
  int row = blockIdx.x;            // b*128 + m'
  int b = row >> 7, mp = row & 127;
  for (int kk = threadIdx.x; kk < 512; kk += 256) {
    int c = kk >> 4, u = kk & 15, d = mp - u;
    float val = (d >= 0) ? v[b * 4096 + c * 128 + d] : 0.f;
    unsigned bits = __float_as_uint(val);
    float rem = val - __uint_as_float(bits & 0xffff0000u);
    Ahx[row * 512 + kk] = (short)(bits >> 16);
    Alx[row * 512 + kk] = (short)(__float_as_uint(rem) >> 16);
  }
}

// ---------------- final conv as MFMA GEMM, zero-LDS, pipelined ----------------
// Block = (b, group g of qn<=2 qt-tiles, k-half). 1280 blocks = 5 blocks/CU
// (round 8's 384-block grid = 1.5 blocks/CU = 1 wave/SIMD was latency-bound at
// MfmaUtil 14%). Explicit 2-stage software pipeline: ks+1's 12 fragments are
// prefetched into 'next' registers before ks's 24 MFMAs issue, hiding L2
// latency within each wave. B-fragments register-reused across the 2 qt tiles.
// All loads 64B-line coalesced; atomics full-line (j>=qn tiles computed but
// never written; Aext rows always in-bounds since qt0-uc+j <= 7).
__global__ __launch_bounds__(256) void k_conv(const short* __restrict__ Ahx,
                                              const short* __restrict__ Alx,
                                              const short* __restrict__ Bh,
                                              const short* __restrict__ Bl,
                                              float* __restrict__ y) {
  const int UC[20]  = {0,0,0,0, 1,1,1,1, 2,2,2, 3,3,3, 4,4, 5,5, 6, 7};
  const int QT0[20] = {0,2,4,6, 1,3,5,7, 2,4,6, 3,5,7, 4,6, 5,7, 6, 7};
  const int QN[20]  = {2,2,2,2, 2,2,2,1, 2,2,2, 2,2,1, 2,2, 2,1, 2, 1};
  int blk = blockIdx.x;            // 1280 = 32 b * 20 groups * 2 k-halves
  int kh = blk & 1;
  int gb = blk >> 1;
  int b = gb / 20, g = gb - b * 20;
  int uc = UC[g], qt0v = QT0[g], qn = QN[g];
  int lane = threadIdx.x & 63, wave = threadIdx.x >> 6;
  int quad = lane >> 4, l15 = lane & 15;
  int nt0 = wave * 4;
  int og = 2 * uc + (quad & 1);    // global u-octet for this quad
  int cq = quad >> 1;              // c = 2*ks + cq
  int ks0 = kh * 8;

  f32x4 acc[2][4];
#pragma unroll
  for (int j = 0; j < 2; ++j)
#pragma unroll
    for (int t = 0; t < 4; ++t) acc[j][t] = (f32x4)0.f;

  const bf16x8* Ah8 = (const bf16x8*)Ahx;
  const bf16x8* Al8 = (const bf16x8*)Alx;
  const bf16x8* Bh8 = (const bf16x8*)Bh;
  const bf16x8* Bl8 = (const bf16x8*)Bl;
  int abase = (b * 128 + (qt0v - uc) * 16 + l15) * 64 + quad + 4 * ks0;  // +1024/j, +4/ks
  int bbase = (cq * 16 + og) * 256 + l15 + nt0 * 16 + ks0 * 8192;        // +16/t, +8192/ks

  bf16x8 cavh[2], cavl[2], cbvh[4], cbvl[4];
#pragma unroll
  for (int j = 0; j < 2; ++j) { cavh[j] = Ah8[abase + j * 1024]; cavl[j] = Al8[abase + j * 1024]; }
#pragma unroll
  for (int t = 0; t < 4; ++t) { cbvh[t] = Bh8[bbase + t * 16]; cbvl[t] = Bl8[bbase + t * 16]; }

#pragma unroll
  for (int ks = 0; ks < 8; ++ks) {
    bf16x8 navh[2], navl[2], nbvh[4], nbvl[4];
    if (ks < 7) {
      int an = abase + 4 * (ks + 1);
      int bn = bbase + (ks + 1) * 8192;
#pragma unroll
      for (int j = 0; j < 2; ++j) { navh[j] = Ah8[an + j * 1024]; navl[j] = Al8[an + j * 1024]; }
#pragma unroll
      for (int t = 0; t < 4; ++t) { nbvh[t] = Bh8[bn + t * 16]; nbvl[t] = Bl8[bn + t * 16]; }
    }
#pragma unroll
    for (int j = 0; j < 2; ++j)
#pragma unroll
      for (int t = 0; t < 4; ++t) {
        MFMA16(acc[j][t], cavh[j], cbvh[t]);
        MFMA16(acc[j][t], cavh[j], cbvl[t]);
        MFMA16(acc[j][t], cavl[j], cbvh[t]);
      }
    if (ks < 7) {
#pragma unroll
      for (int j = 0; j < 2; ++j) { cavh[j] = navh[j]; cavl[j] = navl[j]; }
#pragma unroll
      for (int t = 0; t < 4; ++t) { cbvh[t] = nbvh[t]; cbvl[t] = nbvl[t]; }
    }
  }

#pragma unroll
  for (int j = 0; j < 2; ++j) {
    if (j >= qn) break;
    float* yb = y + b * 32768 + ((qt0v + j) * 16 + quad * 4) * 256 + l15;
#pragma unroll
    for (int t = 0; t < 4; ++t)
#pragma unroll
      for (int reg = 0; reg < 4; ++reg)
        atomicAdd(yb + reg * 256 + (nt0 + t) * 16, acc[j][t][reg]);
  }
}

extern "C" void kernel_launch(void* const* d_in, const int* in_sizes, int n_in,
                              void* d_out, int out_size, void* d_ws, size_t ws_size,
                              hipStream_t stream) {
  const float* audio = (const float*)d_in[0];
  const float* Win   = (const float*)d_in[1];
  const float* bin   = (const float*)d_in[2];
  const float* bw    = (const float*)d_in[3];
  const float* bb    = (const float*)d_in[4];
  const float* Ws    = (const float*)d_in[5];
  const float* bs    = (const float*)d_in[6];
  const float* Wd    = (const float*)d_in[7];
  const float* bd    = (const float*)d_in[8];
  const float* reson = (const float*)d_in[9];

  float* out = (float*)d_out;           // [0,1048576) = y ; [1048576,2097152) = sparse
  float* ws  = (float*)d_ws;

  float* spec   = ws + WS_SPEC;
  float* h0     = ws + WS_H0;
  float* accb   = ws + WS_ACC;
  float* vbuf   = ws + WS_V;
  float* WT     = ws + WS_WTIN;
  float* WsT    = ws + WS_WST;
  float* WdT    = ws + WS_WDT;
  float* frames = ws + WS_FRAMES;
  float* resbuf = ws + WS_RES;
  // frames region is dead after k_res_assemble -> reuse for bf16 B packs
  short* Bh = (short*)(ws + WS_FRAMES);            // 1,048,576 bf16 = 2 MB
  short* Bl = (short*)(ws + WS_FRAMES + 524288u);  // 1,048,576 bf16 = 2 MB
  // chain-weight packs live in WS_V until k_sparse_dense overwrites it (after k_chain)
  short* Whg = (short*)(ws + WS_V);                // 16384 bf16 = 32 KB
  short* Wlg = (short*)(ws + WS_V + 8192u);        // 16384 bf16 = 32 KB
  // spec region is dead after k_proj_in -> reuse for Aext packs (4 MB each)
  short* Ahx = (short*)(ws + WS_SPEC);             // 32*128*512 bf16 = 4 MB
  short* Alx = (short*)(ws + WS_SPEC + 1048576u);  // 32*128*512 bf16 = 4 MB

  // zero y region (atomicAdd target); d_out is poisoned before every launch
  hipMemsetAsync(d_out, 0, 1048576u * sizeof(float), stream);

  k_prep<<<128, 256, 0, stream>>>(Win, Ws, Wd, bw, WT, WsT, WdT, Whg, Wlg);
  k_fft<<<2560, 256, 0, stream>>>(audio, reson, spec, frames);
  k_res_assemble<<<4096, 256, 0, stream>>>(frames, resbuf);
  k_bpack<<<512, 256, 0, stream>>>(resbuf, Bh, Bl);
  k_proj_in<<<512, 256, 0, stream>>>(spec, WT, bin, h0);
  k_chain<<<32, 1024, 0, stream>>>(h0, Whg, Wlg, bb, accb);
  k_sparse_dense<<<4096, 256, 0, stream>>>(accb, WsT, bs, WdT, bd, out + 1048576, vbuf);
  k_apack<<<4096, 256, 0, stream>>>(vbuf, Ahx, Alx);
  k_conv<<<1280, 256, 0, stream>>>(Ahx, Alx, Bh, Bl, out);
}

// Round 11
// 224.632 us; speedup vs baseline: 1.0071x; 1.0071x over previous
//
#include <hip/hip_runtime.h>

#define PI_F 3.14159265358979323846f

typedef short bf16x8 __attribute__((ext_vector_type(8)));
typedef float f32x4 __attribute__((ext_vector_type(4)));

#define MFMA16(acc, a, b) \
  acc = __builtin_amdgcn_mfma_f32_16x16x32_bf16(a, b, acc, 0, 0, 0)

// ---------------- workspace layout (float offsets) ----------------
#define WS_SPEC   0u          // 32*128*1024  [b][t][k]; dead after k_proj_in ->
                              // reused for the Aext bf16 packs (k_apack/k_conv)
#define WS_H0     4194304u    // 32*32*128    [b][o][t]
#define WS_ACC    4325376u    // 32*128*32    [b][t][o]
#define WS_V      4456448u    // 32*32*128    [b][c][t]; ALSO: k_prep stashes the
                              // chain-weight bf16 packs in the first 16384 floats
#define WS_WTIN   4587520u    // 1024*32      [k][o]
#define WS_WST    4620288u    // 32*256       [m][o2]
#define WS_WDT    4628480u    // 256*32       [o2][c]
#define WS_FRAMES 4636672u    // 32*32*2048   [c][f][j]; bf16 B packs live after it
#define WS_RES    6733824u    // (unused now: overlap-add fused into k_bpack)
// total 7782400 floats = ~29.7 MB

// ---- 2048-pt complex DIT FFT, input already in bit-reversed order, 256 thr ----
__device__ __forceinline__ void fft2048_stages(float2* buf, int tid) {
  for (int stage = 0; stage < 11; ++stage) {
    int half = 1 << stage;
    float base = -PI_F / (float)half;   // -2*pi/len
    for (int t = tid; t < 1024; t += 256) {
      int j  = t & (half - 1);
      int i0 = ((t >> stage) << (stage + 1)) + j;
      int i1 = i0 + half;
      float s, c;
      __sincosf(base * (float)j, &s, &c);   // e^{-i*2pi/len*j} = c + i*s
      float2 u = buf[i0];
      float2 w = buf[i1];
      float tr = c * w.x - s * w.y;
      float ti = c * w.y + s * w.x;
      buf[i0] = make_float2(u.x + tr, u.y + ti);
      buf[i1] = make_float2(u.x - tr, u.y - ti);
    }
    __syncthreads();
  }
}

// ---------------- fused FFT kernel: STFT pairs + resonance-frame pairs ----------------
__global__ __launch_bounds__(256) void k_fft(const float* __restrict__ audio,
                                             const float* __restrict__ resin,
                                             float* __restrict__ spec,
                                             float* __restrict__ frames) {
  __shared__ float2 buf[2048];
  int blk = blockIdx.x;
  if (blk < 2048) {
    int b  = blk >> 6;
    int f0 = (blk & 63) * 2;      // frames f0, f0+1
    for (int j = threadIdx.x; j < 2048; j += 256) {
      float h = 0.5f - 0.5f * __cosf(0.0030679615757712823f * (float)j); // 2pi/2048
      int i1 = f0 * 256 + j;
      int i2 = i1 + 256;
      float a1 = (i1 < 32768) ? audio[b * 32768 + i1] : 0.f;
      float a2 = (i2 < 32768) ? audio[b * 32768 + i2] : 0.f;
      buf[__brev((unsigned)j) >> 21] = make_float2(a1 * h, a2 * h);
    }
    __syncthreads();
    fft2048_stages(buf, threadIdx.x);
    const float scale = 0.5f * 0.022097086912079608f;  // 0.5 / sqrt(2048)
    for (int k = threadIdx.x; k < 1024; k += 256) {
      float2 zk = buf[k];
      float2 zn = buf[(2048 - k) & 2047];
      float f1r = zk.x + zn.x, f1i = zk.y - zn.y;
      float f2r = zk.y + zn.y, f2i = zk.x - zn.x;
      spec[(b * 128 + f0) * 1024 + k]     = sqrtf(f1r * f1r + f1i * f1i) * scale;
      spec[(b * 128 + f0 + 1) * 1024 + k] = sqrtf(f2r * f2r + f2i * f2i) * scale;
    }
  } else {
    int r = blk - 2048;           // 0..511
    int c = r >> 4;
    int g = r & 15;               // frames 2g (exp 2g+1), 2g+1 (exp 2g+2)
    float e1 = (float)(2 * g + 1);
    for (int k = threadIdx.x; k < 2048; k += 256) {
      int kk = (k <= 1024) ? k : 2048 - k;   // Hermitian (real) extension
      float cv = resin[c * 1025 + kk];
      cv = fminf(fmaxf(cv, 0.f), 0.9999f);
      float m1 = __powf(cv, e1);
      float m2 = m1 * cv;
      buf[__brev((unsigned)k) >> 21] = make_float2(m1, m2);
    }
    __syncthreads();
    fft2048_stages(buf, threadIdx.x);
    for (int j = threadIdx.x; j < 2048; j += 256) {
      float h  = 0.5f - 0.5f * __cosf(0.0030679615757712823f * (float)j);
      float sc = h * (1.f / 2048.f);
      float2 z = buf[j];
      frames[(c * 32 + 2 * g) * 2048 + j]     = z.x * sc;
      frames[(c * 32 + 2 * g + 1) * 2048 + j] = z.y * sc;
    }
  }
}

// ---------------- weight transposes + chain-weight bf16 hi/lo packs ----------------
__global__ __launch_bounds__(256) void k_prep(const float* __restrict__ Win,
                                              const float* __restrict__ Ws,
                                              const float* __restrict__ Wd,
                                              const float* __restrict__ bwIn,
                                              float* __restrict__ WT,
                                              float* __restrict__ WsT,
                                              float* __restrict__ WdT,
                                              short* __restrict__ Whg,
                                              short* __restrict__ Wlg) {
  int i = blockIdx.x * 256 + threadIdx.x;
  if (i < 32768) { int o = i >> 10, k = i & 1023; WT[k * 32 + o] = Win[i]; }
  if (i < 8192)  { int o2 = i >> 5, m = i & 31;   WsT[m * 256 + o2] = Ws[i]; }
  if (i < 8192)  { int c = i >> 8, o2 = i & 255;  WdT[o2 * 32 + c] = Wd[i]; }
  if (i < 16384) {
    // i = ((s*32+o)*32+m)*2 + w
    int w = i & 1, m = (i >> 1) & 31, o = (i >> 6) & 31, s = i >> 11;
    float val = bwIn[i];
    unsigned bits = __float_as_uint(val);
    float rem = val - __uint_as_float(bits & 0xffff0000u);
    int row = (s * 2 + w) * 32 + o;
    Whg[row * 32 + m] = (short)(bits >> 16);
    Wlg[row * 32 + m] = (short)(__float_as_uint(rem) >> 16);
  }
}

// ---------------- proj_in: h0[b,o,t] = sum_k WT[k][o]*spec[b,t,k] + bias ----------------
__global__ __launch_bounds__(256) void k_proj_in(const float* __restrict__ spec,
                                                 const float* __restrict__ WT,
                                                 const float* __restrict__ bias,
                                                 float* __restrict__ h0) {
  __shared__ float specL[8][1024];
  __shared__ float red[32][8][8];   // [o][tt][p]
  int b  = blockIdx.x >> 4;
  int t0 = (blockIdx.x & 15) * 8;
  for (int i = threadIdx.x; i < 8192; i += 256) {
    int tt = i >> 10, k = i & 1023;
    specL[tt][k] = spec[(b * 128 + t0 + tt) * 1024 + k];
  }
  __syncthreads();
  int o = threadIdx.x & 31, p = threadIdx.x >> 5;
  float part[8] = {0.f,0.f,0.f,0.f,0.f,0.f,0.f,0.f};
  for (int i = 0; i < 128; ++i) {
    int k = p * 128 + ((i + p * 4) & 127);   // stagger: conflict-free banks across p
    float w = WT[k * 32 + o];
#pragma unroll
    for (int tt = 0; tt < 8; ++tt) part[tt] += w * specL[tt][k];
  }
#pragma unroll
  for (int tt = 0; tt < 8; ++tt) red[o][tt][p] = part[tt];
  __syncthreads();
  int oo = threadIdx.x >> 3, tt2 = threadIdx.x & 7;
  float s = bias[oo];
#pragma unroll
  for (int p2 = 0; p2 < 8; ++p2) s += red[oo][tt2][p2];
  h0[b * 4096 + oo * 128 + t0 + tt2] = s;
}

// ---------------- 8-block anticausal chain as per-step MFMA GEMM pairs ----------------
__global__ __launch_bounds__(1024) void k_chain(const float* __restrict__ h0,
                                                const short* __restrict__ Whg,
                                                const short* __restrict__ Wlg,
                                                const float* __restrict__ bb,
                                                float* __restrict__ accout) {
  __shared__ __align__(16) short Hh[192 * 40];   // rows stride 40 bf16 (80 B)
  __shared__ __align__(16) short Hl[192 * 40];
  __shared__ float Hf[128 * 33];                 // fp32 H for exact residual
  __shared__ float bL[256];
  __shared__ float red[16];
  int b = blockIdx.x, tid = threadIdx.x;

  for (int i = tid; i < 4096; i += 1024) {
    int t = i & 127;                 // h0 layout [o][t]
    int o = i >> 7;
    float val = h0[b * 4096 + i];
    Hf[t * 33 + o] = val;
    unsigned bits = __float_as_uint(val);
    float rem = val - __uint_as_float(bits & 0xffff0000u);
    Hh[t * 40 + o] = (short)(bits >> 16);
    Hl[t * 40 + o] = (short)(__float_as_uint(rem) >> 16);
  }
  for (int i = tid; i < 64 * 40; i += 1024) {    // zero pad rows 128..191
    Hh[128 * 40 + i] = 0;
    Hl[128 * 40 + i] = 0;
  }
  if (tid < 256) bL[tid] = bb[tid];
  __syncthreads();

  int wave = tid >> 6, lane = tid & 63;
  int quad = lane >> 4, l15 = lane & 15;
  int t0 = (wave & 7) * 16, o0 = (wave >> 3) * 16;
  int tD = t0 + quad * 4;          // D rows tD..tD+3
  int oD = o0 + l15;               // D col

  const bf16x8* Hh8 = (const bf16x8*)Hh;   // unit = row*5 + quad (40 bf16 = 5 units)
  const bf16x8* Hl8 = (const bf16x8*)Hl;
  const bf16x8* Wh8 = (const bf16x8*)Whg;  // unit = row*4 + quad (32 bf16 = 4 units)
  const bf16x8* Wl8 = (const bf16x8*)Wlg;

  float accsum[4] = {0.f, 0.f, 0.f, 0.f};
  const int DIL[8] = {1, 2, 4, 8, 16, 32, 64, 1};

#pragma unroll
  for (int s = 0; s < 8; ++s) {
    int arow = t0 + l15;
    int frow = arow + DIL[s];        // <= 191, pad rows give zeros
    bf16x8 Ah = Hh8[arow * 5 + quad];
    bf16x8 Al = Hl8[arow * 5 + quad];
    bf16x8 Fh = Hh8[frow * 5 + quad];
    bf16x8 Fl = Hl8[frow * 5 + quad];
    int w0row = ((s * 2 + 0) * 32 + oD) * 4 + quad;
    int w1row = ((s * 2 + 1) * 32 + oD) * 4 + quad;
    bf16x8 B0h = Wh8[w0row], B0l = Wl8[w0row];
    bf16x8 B1h = Wh8[w1row], B1l = Wl8[w1row];
    float bias = bL[s * 32 + oD];
    f32x4 acc = {bias, bias, bias, bias};
    MFMA16(acc, Ah, B0h); MFMA16(acc, Ah, B0l); MFMA16(acc, Al, B0h);
    MFMA16(acc, Fh, B1h); MFMA16(acc, Fh, B1l); MFMA16(acc, Fl, B1h);
    float hnew[4], lmax = 0.f;
#pragma unroll
    for (int r = 0; r < 4; ++r) {
      float sv = acc[r];
      sv = (sv > 0.f) ? sv : 0.2f * sv;       // leaky_relu 0.2
      sv += Hf[(tD + r) * 33 + oD];           // residual (exact fp32)
      hnew[r] = sv;
      lmax = fmaxf(lmax, fabsf(sv));
    }
#pragma unroll
    for (int off = 32; off > 0; off >>= 1)
      lmax = fmaxf(lmax, __shfl_down(lmax, off, 64));
    if (lane == 0) red[wave] = lmax;
    __syncthreads();                 // red visible; all H reads of this step done
    float mx = red[0];
#pragma unroll
    for (int i = 1; i < 16; ++i) mx = fmaxf(mx, red[i]);
    float nm = 1.f / (mx + 1e-8f);
#pragma unroll
    for (int r = 0; r < 4; ++r) {
      float hv = hnew[r] * nm;
      accsum[r] += hv;
      int t = tD + r;
      Hf[t * 33 + oD] = hv;
      unsigned bits = __float_as_uint(hv);
      float rem = hv - __uint_as_float(bits & 0xffff0000u);
      Hh[t * 40 + oD] = (short)(bits >> 16);
      Hl[t * 40 + oD] = (short)(__float_as_uint(rem) >> 16);
    }
    __syncthreads();                 // new H visible for next step
  }
#pragma unroll
  for (int r = 0; r < 4; ++r)
    accout[b * 4096 + (tD + r) * 32 + oD] = accsum[r];
}

// ---------------- sparse (relu proj 32->256, to d_out) + dense (256->32, to ws) ----------------
__global__ __launch_bounds__(256) void k_sparse_dense(const float* __restrict__ acc,
                                                      const float* __restrict__ WsT,
                                                      const float* __restrict__ bs,
                                                      const float* __restrict__ WdT,
                                                      const float* __restrict__ bd,
                                                      float* __restrict__ out_sparse,
                                                      float* __restrict__ v) {
  __shared__ float accL[32];
  __shared__ float sL[256];
  __shared__ float red[8][32];
  int b = blockIdx.x >> 7, t = blockIdx.x & 127;
  int tid = threadIdx.x;
  if (tid < 32) accL[tid] = acc[b * 4096 + t * 32 + tid];
  __syncthreads();
  float s = bs[tid];
  for (int m = 0; m < 32; ++m) s += WsT[m * 256 + tid] * accL[m];
  s = fmaxf(s, 0.f);
  out_sparse[b * 32768 + tid * 128 + t] = s;
  sL[tid] = s;
  __syncthreads();
  int c = tid & 31, p = tid >> 5;
  float part = 0.f;
  for (int j = 0; j < 32; ++j) {
    int o2 = p * 32 + j;
    part += WdT[o2 * 32 + c] * sL[o2];
  }
  red[p][c] = part;
  __syncthreads();
  if (tid < 32) {
    float vv = bd[tid];
    for (int p2 = 0; p2 < 8; ++p2) vv += red[p2][tid];
    v[b * 4096 + tid * 128 + t] = vv;
  }
}

// ---------------- B-pack: overlap-add (fused) + bf16 hi/lo fragment pack ----------------
// res[c,s] = frames[c][g][j0] + (g>0) frames[c][g-1][j0+1024]; s=(8o+j)*256+r.
// Unit (bf16x8) index = ((c*16 + o)*16 + nt)*16 + n holds res[c,(8o+j)*256+nt*16+n].
__global__ __launch_bounds__(256) void k_bpack(const float* __restrict__ frames,
                                               short* __restrict__ Bh,
                                               short* __restrict__ Bl) {
  int c = blockIdx.x >> 4, o = blockIdx.x & 15;
  int r = threadIdx.x;
  bf16x8 hv, lv;
#pragma unroll
  for (int j = 0; j < 8; ++j) {
    int s = (8 * o + j) * 256 + r;
    int g = s >> 10, j0 = s & 1023;
    float val = frames[(c * 32 + g) * 2048 + j0];
    if (g > 0) val += frames[(c * 32 + g - 1) * 2048 + j0 + 1024];
    unsigned bits = __float_as_uint(val);
    float rem = val - __uint_as_float(bits & 0xffff0000u);
    hv[j] = (short)(bits >> 16);
    lv[j] = (short)(__float_as_uint(rem) >> 16);
  }
  int unit = (blockIdx.x * 16 + (r >> 4)) * 16 + (r & 15);
  ((bf16x8*)Bh)[unit] = hv;
  ((bf16x8*)Bl)[unit] = lv;
}

// ---------------- A-pack: extended Toeplitz Aext[b][m'][kk], bf16 hi/lo ----------------
__global__ __launch_bounds__(256) void k_apack(const float* __restrict__ v,
                                               short* __restrict__ Ahx,
                                               short* __restrict__ Alx) {
  int row = blockIdx.x;            // b*128 + m'
  int b = row >> 7, mp = row & 127;
  for (int kk = threadIdx.x; kk < 512; kk += 256) {
    int c = kk >> 4, u = kk & 15, d = mp - u;
    float val = (d >= 0) ? v[b * 4096 + c * 128 + d] : 0.f;
    unsigned bits = __float_as_uint(val);
    float rem = val - __uint_as_float(bits & 0xffff0000u);
    Ahx[row * 512 + kk] = (short)(bits >> 16);
    Alx[row * 512 + kk] = (short)(__float_as_uint(rem) >> 16);
  }
}

// ---------------- final conv as MFMA GEMM, LDS-blocked for locality ----------------
// Round-9 lesson: 490 MB of per-wave global fragment streaming vs 12 MB working
// set that fits no XCD L2 -> L2-miss-bound at 50us regardless of occupancy.
// New blocking: block = (uc, nq 64-col group, kh K-half, bgi b-pair). B tile
// (64 KB) staged ONCE in LDS, reused by 4 waves x 2 b x 2 qt (B traffic
// 328->64 MB, LDS-served). Wave w owns qt-pair {uc+2w, uc+2w+1} and ALL 4
// n-tiles -> 24 MFMA per 12 fragment loads, 8 independent acc chains. A frags
// from global (distinct rows per wave, no dup); bgi in low-3 blockIdx bits ->
// same-b blocks on same XCD (round-robin) -> A slice ~1 MB/XCD L2-resident.
// One barrier total. Idle waves (2w >= 8-uc) exit after it.
__global__ __launch_bounds__(256) void k_conv(const short* __restrict__ Ahx,
                                              const short* __restrict__ Alx,
                                              const short* __restrict__ Bh,
                                              const short* __restrict__ Bl,
                                              float* __restrict__ y) {
  __shared__ __align__(16) short Blds[4096 * 8];   // 4096 b128-units = 64 KB
  int blk = blockIdx.x;            // 1024 = 8 uc * 4 nq * 2 kh * 16 bgi
  int bgi = blk & 15;
  int kh  = (blk >> 4) & 1;
  int nq  = (blk >> 5) & 3;
  int uc  = blk >> 7;
  int ks0 = kh * 8;
  int tid = threadIdx.x;
  int wave = tid >> 6, lane = tid & 63, quad = lane >> 4, l15 = lane & 15;

  const bf16x8* Bh8 = (const bf16x8*)Bh;
  const bf16x8* Bl8 = (const bf16x8*)Bl;
  const bf16x8* Ah8 = (const bf16x8*)Ahx;
  const bf16x8* Al8 = (const bf16x8*)Alx;
  bf16x8* BL = (bf16x8*)Blds;

  // stage B(uc, kh, cols nq*64..+63): layout unit = ks*512 + hl*256 + nt*64 + qd*16 + l15
  for (int i = tid; i < 4096; i += 256) {
    int ks = i >> 9, hl = (i >> 8) & 1, nt = (i >> 6) & 3, qd = (i >> 4) & 3, l = i & 15;
    int c  = 2 * (ks0 + ks) + (qd >> 1);
    int og = 2 * uc + (qd & 1);
    int g  = (c * 16 + og) * 256 + (nq * 4 + nt) * 16 + l;
    BL[i] = hl ? Bl8[g] : Bh8[g];
  }
  __syncthreads();

  int nqt = 8 - uc;
  if (2 * wave >= nqt) return;     // idle wave; no barriers past this point

  int jj0 = 2 * wave;
#pragma unroll
  for (int bi = 0; bi < 2; ++bi) {
    int b = bgi * 2 + bi;
    f32x4 acc[2][4];
#pragma unroll
    for (int j2 = 0; j2 < 2; ++j2)
#pragma unroll
      for (int nt = 0; nt < 4; ++nt) acc[j2][nt] = (f32x4)0.f;
    int a0 = (b * 128 + jj0 * 16 + l15) * 64 + quad + 4 * ks0;
#pragma unroll
    for (int ks = 0; ks < 8; ++ks) {
      bf16x8 a0h = Ah8[a0 + 4 * ks];
      bf16x8 a0l = Al8[a0 + 4 * ks];
      bf16x8 a1h = Ah8[a0 + 1024 + 4 * ks];    // +16 rows (qt+1); row <= 127 always
      bf16x8 a1l = Al8[a0 + 1024 + 4 * ks];
#pragma unroll
      for (int nt = 0; nt < 4; ++nt) {
        bf16x8 bh_ = BL[ks * 512 + nt * 64 + quad * 16 + l15];
        bf16x8 bl_ = BL[ks * 512 + 256 + nt * 64 + quad * 16 + l15];
        MFMA16(acc[0][nt], a0h, bh_);
        MFMA16(acc[0][nt], a0h, bl_);
        MFMA16(acc[0][nt], a0l, bh_);
        MFMA16(acc[1][nt], a1h, bh_);
        MFMA16(acc[1][nt], a1h, bl_);
        MFMA16(acc[1][nt], a1l, bh_);
      }
    }
#pragma unroll
    for (int j2 = 0; j2 < 2; ++j2) {
      if (jj0 + j2 >= nqt) break;
      int qt = uc + jj0 + j2;
      float* yb = y + b * 32768 + (qt * 16 + quad * 4) * 256 + l15;
#pragma unroll
      for (int nt = 0; nt < 4; ++nt)
#pragma unroll
        for (int reg = 0; reg < 4; ++reg)
          atomicAdd(yb + reg * 256 + nq * 64 + nt * 16, acc[j2][nt][reg]);
    }
  }
}

extern "C" void kernel_launch(void* const* d_in, const int* in_sizes, int n_in,
                              void* d_out, int out_size, void* d_ws, size_t ws_size,
                              hipStream_t stream) {
  const float* audio = (const float*)d_in[0];
  const float* Win   = (const float*)d_in[1];
  const float* bin   = (const float*)d_in[2];
  const float* bw    = (const float*)d_in[3];
  const float* bb    = (const float*)d_in[4];
  const float* Ws    = (const float*)d_in[5];
  const float* bs    = (const float*)d_in[6];
  const float* Wd    = (const float*)d_in[7];
  const float* bd    = (const float*)d_in[8];
  const float* reson = (const float*)d_in[9];

  float* out = (float*)d_out;           // [0,1048576) = y ; [1048576,2097152) = sparse
  float* ws  = (float*)d_ws;

  float* spec   = ws + WS_SPEC;
  float* h0     = ws + WS_H0;
  float* accb   = ws + WS_ACC;
  float* vbuf   = ws + WS_V;
  float* WT     = ws + WS_WTIN;
  float* WsT    = ws + WS_WST;
  float* WdT    = ws + WS_WDT;
  float* frames = ws + WS_FRAMES;
  // frames region tail reuse: B packs placed after k_fft output is consumed
  short* Bh = (short*)(ws + WS_RES);               // 1,048,576 bf16 = 2 MB
  short* Bl = (short*)(ws + WS_RES + 524288u);     // 1,048,576 bf16 = 2 MB
  // chain-weight packs live in WS_V until k_sparse_dense overwrites it (after k_chain)
  short* Whg = (short*)(ws + WS_V);                // 16384 bf16 = 32 KB
  short* Wlg = (short*)(ws + WS_V + 8192u);        // 16384 bf16 = 32 KB
  // spec region is dead after k_proj_in -> reuse for Aext packs (4 MB each)
  short* Ahx = (short*)(ws + WS_SPEC);             // 32*128*512 bf16 = 4 MB
  short* Alx = (short*)(ws + WS_SPEC + 1048576u);  // 32*128*512 bf16 = 4 MB

  // zero y region (atomicAdd target); d_out is poisoned before every launch
  hipMemsetAsync(d_out, 0, 1048576u * sizeof(float), stream);

  k_prep<<<128, 256, 0, stream>>>(Win, Ws, Wd, bw, WT, WsT, WdT, Whg, Wlg);
  k_fft<<<2560, 256, 0, stream>>>(audio, reson, spec, frames);
  k_bpack<<<512, 256, 0, stream>>>(frames, Bh, Bl);
  k_proj_in<<<512, 256, 0, stream>>>(spec, WT, bin, h0);
  k_chain<<<32, 1024, 0, stream>>>(h0, Whg, Wlg, bb, accb);
  k_sparse_dense<<<4096, 256, 0, stream>>>(accb, WsT, bs, WdT, bd, out + 1048576, vbuf);
  k_apack<<<4096, 256, 0, stream>>>(vbuf, Ahx, Alx);
  k_conv<<<1024, 256, 0, stream>>>(Ahx, Alx, Bh, Bl, out);
}